// Round 5
// baseline (773.983 us; speedup 1.0000x reference)
//
#include <hip/hip_runtime.h>

#define B_ 2
#define N_ 20000
#define C_ 256
#define K_ 16
#define H_ 128
#define ROWS (B_ * N_)       // 40000
#define MT 313               // ceil(40000/128)
#define MPAD (MT * 128)      // 40064

typedef __attribute__((ext_vector_type(8))) short bf16x8;
typedef __attribute__((ext_vector_type(4))) float f32x4;

__device__ __forceinline__ float us2f(unsigned short u) {
    return __uint_as_float(((unsigned int)u) << 16);
}
__device__ __forceinline__ unsigned short f2us(float f) {
    unsigned int u = __float_as_uint(f);
    unsigned int r = (u + 0x7fffu + ((u >> 16) & 1u)) >> 16;
    return (unsigned short)r;
}
__device__ __forceinline__ void gld_lds16(const unsigned short* g, unsigned short* l) {
    __builtin_amdgcn_global_load_lds(
        (__attribute__((address_space(1))) void*)(g),
        (__attribute__((address_space(3))) void*)(l), 16, 0, 0);
}
__device__ __forceinline__ void dec8bf(const uint4 u, float* d) {
    d[0] = us2f(u.x & 0xffff); d[1] = us2f(u.x >> 16);
    d[2] = us2f(u.y & 0xffff); d[3] = us2f(u.y >> 16);
    d[4] = us2f(u.z & 0xffff); d[5] = us2f(u.z >> 16);
    d[6] = us2f(u.w & 0xffff); d[7] = us2f(u.w >> 16);
}
__device__ __forceinline__ void dec16f8(const uint4 u, float* d) {
    d[0]  = __builtin_amdgcn_cvt_f32_fp8(u.x, 0);
    d[1]  = __builtin_amdgcn_cvt_f32_fp8(u.x, 1);
    d[2]  = __builtin_amdgcn_cvt_f32_fp8(u.x, 2);
    d[3]  = __builtin_amdgcn_cvt_f32_fp8(u.x, 3);
    d[4]  = __builtin_amdgcn_cvt_f32_fp8(u.y, 0);
    d[5]  = __builtin_amdgcn_cvt_f32_fp8(u.y, 1);
    d[6]  = __builtin_amdgcn_cvt_f32_fp8(u.y, 2);
    d[7]  = __builtin_amdgcn_cvt_f32_fp8(u.y, 3);
    d[8]  = __builtin_amdgcn_cvt_f32_fp8(u.z, 0);
    d[9]  = __builtin_amdgcn_cvt_f32_fp8(u.z, 1);
    d[10] = __builtin_amdgcn_cvt_f32_fp8(u.z, 2);
    d[11] = __builtin_amdgcn_cvt_f32_fp8(u.z, 3);
    d[12] = __builtin_amdgcn_cvt_f32_fp8(u.w, 0);
    d[13] = __builtin_amdgcn_cvt_f32_fp8(u.w, 1);
    d[14] = __builtin_amdgcn_cvt_f32_fp8(u.w, 2);
    d[15] = __builtin_amdgcn_cvt_f32_fp8(u.w, 3);
}

// ---------------- fp32 -> bf16 convert ---------------------------------------
extern "C" __global__ void __launch_bounds__(256)
cvt_kernel(const float* __restrict__ src, unsigned short* __restrict__ dst, int n4) {
    int t = blockIdx.x * 256 + threadIdx.x;
    if (t >= n4) return;
    float4 v = ((const float4*)src)[t];
    ushort4 o;
    o.x = f2us(v.x); o.y = f2us(v.y); o.z = f2us(v.z); o.w = f2us(v.w);
    ((ushort4*)dst)[t] = o;
}

// ---------------- batched weight convert (4 tensors, one dispatch) -----------
extern "C" __global__ void __launch_bounds__(256)
cvtw_kernel(const float* __restrict__ s0, const float* __restrict__ s1,
            const float* __restrict__ s2, const float* __restrict__ s3,
            unsigned short* __restrict__ d0, unsigned short* __restrict__ d1,
            unsigned short* __restrict__ d2, unsigned short* __restrict__ d3) {
    const int y = blockIdx.y;
    const float* src = (y == 0) ? s0 : (y == 1 ? s1 : (y == 2 ? s2 : s3));
    unsigned short* dst = (y == 0) ? d0 : (y == 1 ? d1 : (y == 2 ? d2 : d3));
    const int n4 = (y < 3) ? (3 * C_ * C_ / 4) : (H_ * C_ / 4);
    int t = blockIdx.x * 256 + threadIdx.x;
    if (t >= n4) return;
    float4 v = ((const float4*)src)[t];
    ushort4 o;
    o.x = f2us(v.x); o.y = f2us(v.y); o.z = f2us(v.z); o.w = f2us(v.w);
    ((ushort4*)dst)[t] = o;
}

// ---------------- bf16 MFMA GEMM 128x128 (gate H) ----------------------------
extern "C" __global__ void __launch_bounds__(256)
gemm_bf16(const unsigned short* __restrict__ A, const unsigned short* __restrict__ W,
          const float* __restrict__ bias, unsigned short* __restrict__ O,
          const int Mvalid, const int ldo) {
    const int m0 = blockIdx.x * 128;
    const int tid = threadIdx.x;
    const int w = tid >> 6, lane = tid & 63;
    const int l15 = lane & 15, l4 = lane >> 4;
    const int rowq = (w >> 1) * 64;
    const int colq = (w & 1) * 64;

    __shared__ unsigned short As[128 * 32];
    __shared__ unsigned short Bs[128 * 32];

    f32x4 acc[4][4] = {};
    const int srow = w * 16 + (lane >> 2);
    const int schunk = (lane & 3) * 8;

    for (int k0 = 0; k0 < 256; k0 += 32) {
        __syncthreads();
#pragma unroll
        for (int issue = 0; issue < 2; ++issue) {
            const int ra = m0 + issue * 64 + srow;
            const int rb = issue * 64 + srow;
            gld_lds16(A + (size_t)ra * 256 + k0 + schunk, As + issue * 2048 + w * 512);
            gld_lds16(W + (size_t)rb * 256 + k0 + schunk, Bs + issue * 2048 + w * 512);
        }
        __syncthreads();
        bf16x8 a[4], b[4];
#pragma unroll
        for (int i = 0; i < 4; ++i)
            a[i] = *(const bf16x8*)&As[(rowq + i * 16 + l15) * 32 + l4 * 8];
#pragma unroll
        for (int j = 0; j < 4; ++j)
            b[j] = *(const bf16x8*)&Bs[(colq + j * 16 + l15) * 32 + l4 * 8];
#pragma unroll
        for (int i = 0; i < 4; ++i)
#pragma unroll
            for (int j = 0; j < 4; ++j)
                acc[i][j] = __builtin_amdgcn_mfma_f32_16x16x32_bf16(a[i], b[j], acc[i][j], 0, 0, 0);
    }

#pragma unroll
    for (int j = 0; j < 4; ++j) {
        const int gcol = colq + j * 16 + l15;
        const float bj = bias[gcol];
#pragma unroll
        for (int i = 0; i < 4; ++i) {
#pragma unroll
            for (int r = 0; r < 4; ++r) {
                const int grow = m0 + rowq + i * 16 + l4 * 4 + r;
                if (grow < Mvalid) O[(size_t)grow * ldo + gcol] = f2us(acc[i][j][r] + bj);
            }
        }
    }
}

// ---------------- QKV GEMM: 128x256 tile, 512 threads, 8 waves ---------------
// z=0: O = A0 @ Wq^T + bq   -> bf16 (in-place over A0 is safe)
// z=1: O = A12 @ Wk^T + bk  -> fp8
// z=2: O = A12 @ Wv^T + bv  -> fp8
extern "C" __global__ void __launch_bounds__(512)
gemm_qkv512(const unsigned short* Aq, const unsigned short* __restrict__ A12,
            const unsigned short* __restrict__ Wq, const unsigned short* __restrict__ Wk,
            const unsigned short* __restrict__ Wv, const float* __restrict__ bq,
            const float* __restrict__ bk, const float* __restrict__ bv,
            unsigned short* Oq, unsigned char* __restrict__ Ok,
            unsigned char* __restrict__ Ov, const int Mvalid) {
    const int z = blockIdx.z;
    const unsigned short* A = (z == 0) ? Aq : A12;
    const unsigned short* W = (z == 0) ? Wq : (z == 1 ? Wk : Wv);
    const float* bias = (z == 0) ? bq : (z == 1 ? bk : bv);

    const int m0 = blockIdx.x * 128;
    const int tid = threadIdx.x;
    const int w = tid >> 6, lane = tid & 63;
    const int l15 = lane & 15, l4 = lane >> 4;
    const int mrow = (w >> 2) * 64;    // 2 M-halves
    const int ncol = (w & 3) * 64;     // 4 N-quarters

    __shared__ unsigned short As[128 * 32];   // 8 KB
    __shared__ unsigned short Bs[256 * 32];   // 16 KB

    f32x4 acc[4][4] = {};
    const int srow = w * 16 + (lane >> 2);    // w in [0,8): 128 rows
    const int schunk = (lane & 3) * 8;

    for (int k0 = 0; k0 < 256; k0 += 32) {
        __syncthreads();
        gld_lds16(A + (size_t)(m0 + srow) * 256 + k0 + schunk, As + w * 512);
        gld_lds16(W + (size_t)srow * 256 + k0 + schunk, Bs + w * 512);
        gld_lds16(W + (size_t)(128 + srow) * 256 + k0 + schunk, Bs + 4096 + w * 512);
        __syncthreads();
        bf16x8 a[4], b[4];
#pragma unroll
        for (int i = 0; i < 4; ++i)
            a[i] = *(const bf16x8*)&As[(mrow + i * 16 + l15) * 32 + l4 * 8];
#pragma unroll
        for (int j = 0; j < 4; ++j)
            b[j] = *(const bf16x8*)&Bs[(ncol + j * 16 + l15) * 32 + l4 * 8];
#pragma unroll
        for (int i = 0; i < 4; ++i)
#pragma unroll
            for (int j = 0; j < 4; ++j)
                acc[i][j] = __builtin_amdgcn_mfma_f32_16x16x32_bf16(a[i], b[j], acc[i][j], 0, 0, 0);
    }

    float bj[4];
#pragma unroll
    for (int j = 0; j < 4; ++j) bj[j] = bias[ncol + j * 16 + l15];

    if (z == 0) {
#pragma unroll
        for (int i = 0; i < 4; ++i) {
#pragma unroll
            for (int r = 0; r < 4; ++r) {
                const int grow = m0 + mrow + i * 16 + l4 * 4 + r;
                if (grow < Mvalid) {
                    const size_t base = (size_t)grow * 256 + ncol + l15;
#pragma unroll
                    for (int j = 0; j < 4; ++j)
                        Oq[base + j * 16] = f2us(acc[i][j][r] + bj[j]);
                }
            }
        }
    } else {
        unsigned char* O = (z == 1) ? Ok : Ov;
#pragma unroll
        for (int i = 0; i < 4; ++i) {
#pragma unroll
            for (int r = 0; r < 4; ++r) {
                const int grow = m0 + mrow + i * 16 + l4 * 4 + r;
                if (grow < Mvalid) {
                    const size_t base = (size_t)grow * 256 + ncol + l15;
                    unsigned int p01 = __builtin_amdgcn_cvt_pk_fp8_f32(
                        acc[i][0][r] + bj[0], acc[i][1][r] + bj[1], 0, false);
                    unsigned int p23 = __builtin_amdgcn_cvt_pk_fp8_f32(
                        acc[i][2][r] + bj[2], acc[i][3][r] + bj[3], 0, false);
                    O[base + 0]  = (unsigned char)(p01 & 0xff);
                    O[base + 16] = (unsigned char)((p01 >> 8) & 0xff);
                    O[base + 32] = (unsigned char)(p23 & 0xff);
                    O[base + 48] = (unsigned char)((p23 >> 8) & 0xff);
                }
            }
        }
    }
}

// ---------------- mega attention: gate2 + 3x(attn+LN) + final LN -------------
// 16 lanes per row; lane t owns channels [t*16, t*16+16).
extern "C" __global__ void __launch_bounds__(256)
attn_mega(const unsigned short* __restrict__ Q0, const unsigned short* __restrict__ Q1,
          const unsigned short* __restrict__ Q2, const unsigned char* __restrict__ K0,
          const unsigned char* __restrict__ K1, const unsigned char* __restrict__ K2,
          const unsigned char* __restrict__ V0, const unsigned char* __restrict__ V1,
          const unsigned char* __restrict__ V2, const int* __restrict__ knn,
          const unsigned short* __restrict__ Hbf, const float* __restrict__ Wg2,
          const float* __restrict__ bg2, const float* __restrict__ lng,
          const float* __restrict__ lnb, const float* __restrict__ x3,
          const float* __restrict__ fng, const float* __restrict__ fnb,
          float* __restrict__ out) {
    const int tid = threadIdx.x;
    const int g = tid >> 4;
    const int t = tid & 15;
    const int row = blockIdx.x * 16 + g;
    const int b = row / N_;
    const int n = row - b * N_;
    const int c0 = t * 16;

    // ---- gate: alpha = softmax(relu(H) @ Wg2^T + bg2) ----
    float al[3];
    {
        float h[8];
        dec8bf(*(const uint4*)(Hbf + (size_t)row * H_ + t * 8), h);
#pragma unroll
        for (int c = 0; c < 8; ++c) h[c] = fmaxf(h[c], 0.f);
#pragma unroll
        for (int l = 0; l < 3; ++l) {
            const float* w2 = Wg2 + l * H_ + t * 8;
            float4 wa = *(const float4*)w2;
            float4 wb = *(const float4*)(w2 + 4);
            float p = h[0] * wa.x + h[1] * wa.y + h[2] * wa.z + h[3] * wa.w +
                      h[4] * wb.x + h[5] * wb.y + h[6] * wb.z + h[7] * wb.w;
#pragma unroll
            for (int off = 1; off < 16; off <<= 1) p += __shfl_xor(p, off, 64);
            al[l] = p + bg2[l];
        }
        float m = fmaxf(al[0], fmaxf(al[1], al[2]));
        float e0 = __expf(al[0] - m), e1 = __expf(al[1] - m), e2 = __expf(al[2] - m);
        float inv = 1.f / (e0 + e1 + e2);
        al[0] = e0 * inv; al[1] = e1 * inv; al[2] = e2 * inv;
    }

    // ---- neighbor indices (broadcast loads) ----
    int idxs[K_];
#pragma unroll
    for (int k = 0; k < K_; ++k) idxs[k] = knn[n * K_ + k];

    const unsigned short* Qs[3] = {Q0, Q1, Q2};
    const unsigned char* Ks[3] = {K0, K1, K2};
    const unsigned char* Vs[3] = {V0, V1, V2};

    float fo[16] = {};
#pragma unroll
    for (int i = 0; i < 3; ++i) {
        // Q (bf16)
        float qv[16];
        {
            const unsigned short* qp = Qs[i] + (size_t)row * C_ + c0;
            dec8bf(*(const uint4*)qp, qv);
            dec8bf(*(const uint4*)(qp + 8), qv + 8);
        }
        // pass 1: scores
        float s[K_];
#pragma unroll
        for (int k = 0; k < K_; ++k) {
            float kv[16];
            dec16f8(*(const uint4*)(Ks[i] + ((size_t)b * N_ + idxs[k]) * C_ + c0), kv);
            float p = 0.f;
#pragma unroll
            for (int c = 0; c < 16; ++c) p += qv[c] * kv[c];
#pragma unroll
            for (int off = 1; off < 16; off <<= 1) p += __shfl_xor(p, off, 64);
            s[k] = p * 0.0625f;
        }
        float m = s[0];
#pragma unroll
        for (int k = 1; k < K_; ++k) m = fmaxf(m, s[k]);
        float sum = 0.f;
#pragma unroll
        for (int k = 0; k < K_; ++k) {
            s[k] = __expf(s[k] - m);
            sum += s[k];
        }
        const float inv = 1.f / sum;
        // pass 2: o = sum a_k V_k
        float o[16] = {};
#pragma unroll
        for (int k = 0; k < K_; ++k) {
            const float a = s[k] * inv;
            float vv[16];
            dec16f8(*(const uint4*)(Vs[i] + ((size_t)b * N_ + idxs[k]) * C_ + c0), vv);
#pragma unroll
            for (int c = 0; c < 16; ++c) o[c] += a * vv[c];
        }
        // r = o + Q, per-block LN, alpha-weighted accumulate
        float s1 = 0.f, s2 = 0.f;
#pragma unroll
        for (int c = 0; c < 16; ++c) {
            o[c] += qv[c];
            s1 += o[c];
            s2 += o[c] * o[c];
        }
#pragma unroll
        for (int off = 1; off < 16; off <<= 1) {
            s1 += __shfl_xor(s1, off, 64);
            s2 += __shfl_xor(s2, off, 64);
        }
        const float mean = s1 * (1.f / C_);
        const float var = s2 * (1.f / C_) - mean * mean;
        const float rstd = rsqrtf(var + 1e-5f);
        const float a = al[i];
        const float* gp = lng + i * C_ + c0;
        const float* bp = lnb + i * C_ + c0;
#pragma unroll
        for (int j = 0; j < 4; ++j) {
            float4 gg = *(const float4*)(gp + j * 4);
            float4 bb = *(const float4*)(bp + j * 4);
            fo[j * 4 + 0] += a * ((o[j * 4 + 0] - mean) * rstd * gg.x + bb.x);
            fo[j * 4 + 1] += a * ((o[j * 4 + 1] - mean) * rstd * gg.y + bb.y);
            fo[j * 4 + 2] += a * ((o[j * 4 + 2] - mean) * rstd * gg.z + bb.z);
            fo[j * 4 + 3] += a * ((o[j * 4 + 3] - mean) * rstd * gg.w + bb.w);
        }
    }

    // ---- final LN(fo + x3) -> out ----
    const float* xp = x3 + (size_t)row * C_ + c0;
    float r[16];
    float s1 = 0.f, s2 = 0.f;
#pragma unroll
    for (int j = 0; j < 4; ++j) {
        float4 xv = *(const float4*)(xp + j * 4);
        r[j * 4 + 0] = fo[j * 4 + 0] + xv.x;
        r[j * 4 + 1] = fo[j * 4 + 1] + xv.y;
        r[j * 4 + 2] = fo[j * 4 + 2] + xv.z;
        r[j * 4 + 3] = fo[j * 4 + 3] + xv.w;
    }
#pragma unroll
    for (int c = 0; c < 16; ++c) {
        s1 += r[c];
        s2 += r[c] * r[c];
    }
#pragma unroll
    for (int off = 1; off < 16; off <<= 1) {
        s1 += __shfl_xor(s1, off, 64);
        s2 += __shfl_xor(s2, off, 64);
    }
    const float mean = s1 * (1.f / C_);
    const float var = s2 * (1.f / C_) - mean * mean;
    const float rstd = rsqrtf(var + 1e-5f);
    const float* gp = fng + c0;
    const float* bp = fnb + c0;
    float* op = out + (size_t)row * C_ + c0;
#pragma unroll
    for (int j = 0; j < 4; ++j) {
        float4 gg = *(const float4*)(gp + j * 4);
        float4 bb = *(const float4*)(bp + j * 4);
        float4 y;
        y.x = (r[j * 4 + 0] - mean) * rstd * gg.x + bb.x;
        y.y = (r[j * 4 + 1] - mean) * rstd * gg.y + bb.y;
        y.z = (r[j * 4 + 2] - mean) * rstd * gg.z + bb.z;
        y.w = (r[j * 4 + 3] - mean) * rstd * gg.w + bb.w;
        *(float4*)(op + j * 4) = y;
    }
}

extern "C" void kernel_launch(void* const* d_in, const int* in_sizes, int n_in,
                              void* d_out, int out_size, void* d_ws, size_t ws_size,
                              hipStream_t stream) {
    const float* x0 = (const float*)d_in[0];
    const float* x1 = (const float*)d_in[1];
    const float* x2 = (const float*)d_in[2];
    const float* x3 = (const float*)d_in[3];
    const int* knn = (const int*)d_in[4];
    const float* Wq = (const float*)d_in[5];
    const float* bq = (const float*)d_in[6];
    const float* Wk = (const float*)d_in[7];
    const float* bk = (const float*)d_in[8];
    const float* Wv = (const float*)d_in[9];
    const float* bv = (const float*)d_in[10];
    const float* ln_g = (const float*)d_in[11];
    const float* ln_b = (const float*)d_in[12];
    const float* Wg1 = (const float*)d_in[13];
    const float* bg1 = (const float*)d_in[14];
    const float* Wg2 = (const float*)d_in[15];
    const float* bg2 = (const float*)d_in[16];
    const float* fn_g = (const float*)d_in[17];
    const float* fn_b = (const float*)d_in[18];
    float* out = (float*)d_out;

    unsigned char* w8 = (unsigned char*)d_ws;
    const size_t XBF = (size_t)MPAD * C_ * 2;   // 20,512,768 B  (bf16 M x 256)
    const size_t X8 = (size_t)MPAD * C_;        // 10,256,384 B  (fp8  M x 256)
    const size_t HBF = (size_t)MPAD * H_ * 2;   // 10,256,384 B
    const size_t WBLOB = (size_t)3 * C_ * C_ * 2;

    unsigned short* x3bf = (unsigned short*)(w8);
    unsigned short* Qbf[3];
    for (int i = 0; i < 3; ++i) Qbf[i] = (unsigned short*)(w8 + XBF * (1 + i));
    unsigned char* Kf8[3];
    unsigned char* Vf8[3];
    for (int i = 0; i < 3; ++i) {
        Kf8[i] = w8 + 4 * XBF + X8 * i;
        Vf8[i] = w8 + 4 * XBF + 3 * X8 + X8 * i;
    }
    unsigned short* Hbf = (unsigned short*)(w8 + 4 * XBF + 6 * X8);
    unsigned short* wqbf = (unsigned short*)(w8 + 4 * XBF + 6 * X8 + HBF);
    unsigned short* wkbf = (unsigned short*)(w8 + 4 * XBF + 6 * X8 + HBF + WBLOB);
    unsigned short* wvbf = (unsigned short*)(w8 + 4 * XBF + 6 * X8 + HBF + 2 * WBLOB);
    unsigned short* wg1bf = (unsigned short*)(w8 + 4 * XBF + 6 * X8 + HBF + 3 * WBLOB);
    // total ~155.4 MB

    const int xn4 = ROWS * C_ / 4;
    const int wn4 = 3 * C_ * C_ / 4;

    cvt_kernel<<<(xn4 + 255) / 256, 256, 0, stream>>>(x3, x3bf, xn4);
    cvtw_kernel<<<dim3((wn4 + 255) / 256, 4), 256, 0, stream>>>(
        Wq, Wk, Wv, Wg1, wqbf, wkbf, wvbf, wg1bf);

    // gate layer 1: H = x3 @ Wg1^T + bg1
    gemm_bf16<<<dim3(MT, 1, 1), 256, 0, stream>>>(x3bf, wg1bf, bg1, Hbf, ROWS, H_);

    const float* xq[3] = {x0, x1, x2};
    for (int i = 0; i < 3; ++i) {
        cvt_kernel<<<(xn4 + 255) / 256, 256, 0, stream>>>(xq[i], Qbf[i], xn4);
        gemm_qkv512<<<dim3(MT, 1, 3), 512, 0, stream>>>(
            Qbf[i], x3bf, wqbf + (size_t)i * C_ * C_, wkbf + (size_t)i * C_ * C_,
            wvbf + (size_t)i * C_ * C_, bq + i * C_, bk + i * C_, bv + i * C_,
            Qbf[i], Kf8[i], Vf8[i], ROWS);
    }

    attn_mega<<<ROWS / 16, 256, 0, stream>>>(
        Qbf[0], Qbf[1], Qbf[2], Kf8[0], Kf8[1], Kf8[2], Vf8[0], Vf8[1], Vf8[2],
        knn, Hbf, Wg2, bg2, ln_g, ln_b, x3, fn_g, fn_b, out);
}

// Round 6
// 678.069 us; speedup vs baseline: 1.1415x; 1.1415x over previous
//
#include <hip/hip_runtime.h>

#define B_ 2
#define N_ 20000
#define C_ 256
#define K_ 16
#define H_ 128
#define ROWS (B_ * N_)       // 40000
#define MT 313               // ceil(40000/128)
#define MPAD (MT * 128)      // 40064

typedef __attribute__((ext_vector_type(8))) short bf16x8;
typedef __attribute__((ext_vector_type(4))) float f32x4;

__device__ __forceinline__ float us2f(unsigned short u) {
    return __uint_as_float(((unsigned int)u) << 16);
}
__device__ __forceinline__ unsigned short f2us(float f) {
    unsigned int u = __float_as_uint(f);
    unsigned int r = (u + 0x7fffu + ((u >> 16) & 1u)) >> 16;
    return (unsigned short)r;
}
__device__ __forceinline__ float wred(float v) {
#pragma unroll
    for (int off = 32; off > 0; off >>= 1) v += __shfl_xor(v, off, 64);
    return v;
}
__device__ __forceinline__ void gld_lds16(const unsigned short* g, unsigned short* l) {
    __builtin_amdgcn_global_load_lds(
        (__attribute__((address_space(1))) void*)(g),
        (__attribute__((address_space(3))) void*)(l), 16, 0, 0);
}
__device__ __forceinline__ void dec8bf(const uint4 u, float* d) {
    d[0] = us2f(u.x & 0xffff); d[1] = us2f(u.x >> 16);
    d[2] = us2f(u.y & 0xffff); d[3] = us2f(u.y >> 16);
    d[4] = us2f(u.z & 0xffff); d[5] = us2f(u.z >> 16);
    d[6] = us2f(u.w & 0xffff); d[7] = us2f(u.w >> 16);
}
__device__ __forceinline__ void dec16f8(const uint4 u, float* d) {
    d[0]  = __builtin_amdgcn_cvt_f32_fp8(u.x, 0);
    d[1]  = __builtin_amdgcn_cvt_f32_fp8(u.x, 1);
    d[2]  = __builtin_amdgcn_cvt_f32_fp8(u.x, 2);
    d[3]  = __builtin_amdgcn_cvt_f32_fp8(u.x, 3);
    d[4]  = __builtin_amdgcn_cvt_f32_fp8(u.y, 0);
    d[5]  = __builtin_amdgcn_cvt_f32_fp8(u.y, 1);
    d[6]  = __builtin_amdgcn_cvt_f32_fp8(u.y, 2);
    d[7]  = __builtin_amdgcn_cvt_f32_fp8(u.y, 3);
    d[8]  = __builtin_amdgcn_cvt_f32_fp8(u.z, 0);
    d[9]  = __builtin_amdgcn_cvt_f32_fp8(u.z, 1);
    d[10] = __builtin_amdgcn_cvt_f32_fp8(u.z, 2);
    d[11] = __builtin_amdgcn_cvt_f32_fp8(u.z, 3);
    d[12] = __builtin_amdgcn_cvt_f32_fp8(u.w, 0);
    d[13] = __builtin_amdgcn_cvt_f32_fp8(u.w, 1);
    d[14] = __builtin_amdgcn_cvt_f32_fp8(u.w, 2);
    d[15] = __builtin_amdgcn_cvt_f32_fp8(u.w, 3);
}

// ---------------- fp32 -> bf16 convert ---------------------------------------
extern "C" __global__ void __launch_bounds__(256)
cvt_kernel(const float* __restrict__ src, unsigned short* __restrict__ dst, int n4) {
    int t = blockIdx.x * 256 + threadIdx.x;
    if (t >= n4) return;
    float4 v = ((const float4*)src)[t];
    ushort4 o;
    o.x = f2us(v.x); o.y = f2us(v.y); o.z = f2us(v.z); o.w = f2us(v.w);
    ((ushort4*)dst)[t] = o;
}

// ---------------- batched weight convert (4 tensors, one dispatch) -----------
extern "C" __global__ void __launch_bounds__(256)
cvtw_kernel(const float* __restrict__ s0, const float* __restrict__ s1,
            const float* __restrict__ s2, const float* __restrict__ s3,
            unsigned short* __restrict__ d0, unsigned short* __restrict__ d1,
            unsigned short* __restrict__ d2, unsigned short* __restrict__ d3) {
    const int y = blockIdx.y;
    const float* src = (y == 0) ? s0 : (y == 1 ? s1 : (y == 2 ? s2 : s3));
    unsigned short* dst = (y == 0) ? d0 : (y == 1 ? d1 : (y == 2 ? d2 : d3));
    const int n4 = (y < 3) ? (3 * C_ * C_ / 4) : (H_ * C_ / 4);
    int t = blockIdx.x * 256 + threadIdx.x;
    if (t >= n4) return;
    float4 v = ((const float4*)src)[t];
    ushort4 o;
    o.x = f2us(v.x); o.y = f2us(v.y); o.z = f2us(v.z); o.w = f2us(v.w);
    ((ushort4*)dst)[t] = o;
}

// ---------------- bf16 MFMA GEMM 128x128 (gate H) ----------------------------
extern "C" __global__ void __launch_bounds__(256)
gemm_bf16(const unsigned short* __restrict__ A, const unsigned short* __restrict__ W,
          const float* __restrict__ bias, unsigned short* __restrict__ O,
          const int Mvalid, const int ldo) {
    const int m0 = blockIdx.x * 128;
    const int tid = threadIdx.x;
    const int w = tid >> 6, lane = tid & 63;
    const int l15 = lane & 15, l4 = lane >> 4;
    const int rowq = (w >> 1) * 64;
    const int colq = (w & 1) * 64;

    __shared__ unsigned short As[128 * 32];
    __shared__ unsigned short Bs[128 * 32];

    f32x4 acc[4][4] = {};
    const int srow = w * 16 + (lane >> 2);
    const int schunk = (lane & 3) * 8;

    for (int k0 = 0; k0 < 256; k0 += 32) {
        __syncthreads();
#pragma unroll
        for (int issue = 0; issue < 2; ++issue) {
            const int ra = m0 + issue * 64 + srow;
            const int rb = issue * 64 + srow;
            gld_lds16(A + (size_t)ra * 256 + k0 + schunk, As + issue * 2048 + w * 512);
            gld_lds16(W + (size_t)rb * 256 + k0 + schunk, Bs + issue * 2048 + w * 512);
        }
        __syncthreads();
        bf16x8 a[4], b[4];
#pragma unroll
        for (int i = 0; i < 4; ++i)
            a[i] = *(const bf16x8*)&As[(rowq + i * 16 + l15) * 32 + l4 * 8];
#pragma unroll
        for (int j = 0; j < 4; ++j)
            b[j] = *(const bf16x8*)&Bs[(colq + j * 16 + l15) * 32 + l4 * 8];
#pragma unroll
        for (int i = 0; i < 4; ++i)
#pragma unroll
            for (int j = 0; j < 4; ++j)
                acc[i][j] = __builtin_amdgcn_mfma_f32_16x16x32_bf16(a[i], b[j], acc[i][j], 0, 0, 0);
    }

#pragma unroll
    for (int j = 0; j < 4; ++j) {
        const int gcol = colq + j * 16 + l15;
        const float bj = bias[gcol];
#pragma unroll
        for (int i = 0; i < 4; ++i) {
#pragma unroll
            for (int r = 0; r < 4; ++r) {
                const int grow = m0 + rowq + i * 16 + l4 * 4 + r;
                if (grow < Mvalid) O[(size_t)grow * ldo + gcol] = f2us(acc[i][j][r] + bj);
            }
        }
    }
}

// ---------------- QKV GEMM: 128x256 tile, 512 threads, 8 waves ---------------
extern "C" __global__ void __launch_bounds__(512)
gemm_qkv512(const unsigned short* Aq, const unsigned short* __restrict__ A12,
            const unsigned short* __restrict__ Wq, const unsigned short* __restrict__ Wk,
            const unsigned short* __restrict__ Wv, const float* __restrict__ bq,
            const float* __restrict__ bk, const float* __restrict__ bv,
            unsigned short* Oq, unsigned char* __restrict__ Ok,
            unsigned char* __restrict__ Ov, const int Mvalid) {
    const int z = blockIdx.z;
    const unsigned short* A = (z == 0) ? Aq : A12;
    const unsigned short* W = (z == 0) ? Wq : (z == 1 ? Wk : Wv);
    const float* bias = (z == 0) ? bq : (z == 1 ? bk : bv);

    const int m0 = blockIdx.x * 128;
    const int tid = threadIdx.x;
    const int w = tid >> 6, lane = tid & 63;
    const int l15 = lane & 15, l4 = lane >> 4;
    const int mrow = (w >> 2) * 64;
    const int ncol = (w & 3) * 64;

    __shared__ unsigned short As[128 * 32];
    __shared__ unsigned short Bs[256 * 32];

    f32x4 acc[4][4] = {};
    const int srow = w * 16 + (lane >> 2);
    const int schunk = (lane & 3) * 8;

    for (int k0 = 0; k0 < 256; k0 += 32) {
        __syncthreads();
        gld_lds16(A + (size_t)(m0 + srow) * 256 + k0 + schunk, As + w * 512);
        gld_lds16(W + (size_t)srow * 256 + k0 + schunk, Bs + w * 512);
        gld_lds16(W + (size_t)(128 + srow) * 256 + k0 + schunk, Bs + 4096 + w * 512);
        __syncthreads();
        bf16x8 a[4], b[4];
#pragma unroll
        for (int i = 0; i < 4; ++i)
            a[i] = *(const bf16x8*)&As[(mrow + i * 16 + l15) * 32 + l4 * 8];
#pragma unroll
        for (int j = 0; j < 4; ++j)
            b[j] = *(const bf16x8*)&Bs[(ncol + j * 16 + l15) * 32 + l4 * 8];
#pragma unroll
        for (int i = 0; i < 4; ++i)
#pragma unroll
            for (int j = 0; j < 4; ++j)
                acc[i][j] = __builtin_amdgcn_mfma_f32_16x16x32_bf16(a[i], b[j], acc[i][j], 0, 0, 0);
    }

    float bj[4];
#pragma unroll
    for (int j = 0; j < 4; ++j) bj[j] = bias[ncol + j * 16 + l15];

    if (z == 0) {
#pragma unroll
        for (int i = 0; i < 4; ++i) {
#pragma unroll
            for (int r = 0; r < 4; ++r) {
                const int grow = m0 + mrow + i * 16 + l4 * 4 + r;
                if (grow < Mvalid) {
                    const size_t base = (size_t)grow * 256 + ncol + l15;
#pragma unroll
                    for (int j = 0; j < 4; ++j)
                        Oq[base + j * 16] = f2us(acc[i][j][r] + bj[j]);
                }
            }
        }
    } else {
        unsigned char* O = (z == 1) ? Ok : Ov;
#pragma unroll
        for (int i = 0; i < 4; ++i) {
#pragma unroll
            for (int r = 0; r < 4; ++r) {
                const int grow = m0 + mrow + i * 16 + l4 * 4 + r;
                if (grow < Mvalid) {
                    const size_t base = (size_t)grow * 256 + ncol + l15;
                    unsigned int p01 = __builtin_amdgcn_cvt_pk_fp8_f32(
                        acc[i][0][r] + bj[0], acc[i][1][r] + bj[1], 0, false);
                    unsigned int p23 = __builtin_amdgcn_cvt_pk_fp8_f32(
                        acc[i][2][r] + bj[2], acc[i][3][r] + bj[3], 0, false);
                    O[base + 0]  = (unsigned char)(p01 & 0xff);
                    O[base + 16] = (unsigned char)((p01 >> 8) & 0xff);
                    O[base + 32] = (unsigned char)(p23 & 0xff);
                    O[base + 48] = (unsigned char)((p23 >> 8) & 0xff);
                }
            }
        }
    }
}

// ---------------- gate stage 2: alpha = softmax(relu(H)@Wg2^T + bg2) ---------
extern "C" __global__ void __launch_bounds__(256)
gate2_kernel(const unsigned short* __restrict__ Hbf, const float* __restrict__ Wg2,
             const float* __restrict__ bg2, float* __restrict__ alpha) {
    const int tid = threadIdx.x;
    const int w = tid >> 6, lane = tid & 63;
    const int row = blockIdx.x * 4 + w;
    const float h0 = fmaxf(us2f(Hbf[(size_t)row * H_ + lane]), 0.f);
    const float h1 = fmaxf(us2f(Hbf[(size_t)row * H_ + 64 + lane]), 0.f);
    float lg[3];
#pragma unroll
    for (int l = 0; l < 3; ++l) {
        const float* w2 = Wg2 + l * H_;
        lg[l] = wred(h0 * w2[lane] + h1 * w2[lane + 64]) + bg2[l];
    }
    float m = fmaxf(lg[0], fmaxf(lg[1], lg[2]));
    float e0 = __expf(lg[0] - m), e1 = __expf(lg[1] - m), e2 = __expf(lg[2] - m);
    float inv = 1.f / (e0 + e1 + e2);
    if (lane == 0) {
        alpha[row * 3 + 0] = e0 * inv;
        alpha[row * 3 + 1] = e1 * inv;
        alpha[row * 3 + 2] = e2 * inv;
    }
}

// ---------------- attention + LN + alpha-accumulate; iblk==2 fuses final LN --
// 16 lanes per row; lane t owns channels [t*16, t*16+16).
extern "C" __global__ void __launch_bounds__(256)
attn_kernel(const unsigned short* __restrict__ q, const unsigned char* __restrict__ kf,
            const unsigned char* __restrict__ vf, const int* __restrict__ knn,
            const float* __restrict__ alpha, const float* __restrict__ lng,
            const float* __restrict__ lnb, float* __restrict__ accum,
            const float* __restrict__ x3, const float* __restrict__ fng,
            const float* __restrict__ fnb, const int iblk) {
    const int tid = threadIdx.x;
    const int g = tid >> 4;
    const int t = tid & 15;
    const int row = blockIdx.x * 16 + g;
    const int b = row / N_;
    const int n = row - b * N_;
    const int c0 = t * 16;

    // ---- Q (bf16, 16 contiguous channels) ----
    float qv[16];
    {
        const unsigned short* qp = q + (size_t)row * C_ + c0;
        dec8bf(*(const uint4*)qp, qv);
        dec8bf(*(const uint4*)(qp + 8), qv + 8);
    }

    // ---- pass 1: scores ----
    int idxs[K_];
    float s[K_];
#pragma unroll
    for (int k = 0; k < K_; ++k) {
        idxs[k] = knn[n * K_ + k];
        float kv[16];
        dec16f8(*(const uint4*)(kf + ((size_t)b * N_ + idxs[k]) * C_ + c0), kv);
        float p = 0.f;
#pragma unroll
        for (int c = 0; c < 16; ++c) p += qv[c] * kv[c];
#pragma unroll
        for (int off = 1; off < 16; off <<= 1) p += __shfl_xor(p, off, 64);
        s[k] = p * 0.0625f;
    }

    // ---- softmax over 16 ----
    float m = s[0];
#pragma unroll
    for (int k = 1; k < K_; ++k) m = fmaxf(m, s[k]);
    float sum = 0.f;
#pragma unroll
    for (int k = 0; k < K_; ++k) {
        s[k] = __expf(s[k] - m);
        sum += s[k];
    }
    const float inv = 1.f / sum;

    // ---- pass 2: o = (sum_k s_k V_k) * inv ----
    float o[16] = {};
#pragma unroll
    for (int k = 0; k < K_; ++k) {
        float vv[16];
        dec16f8(*(const uint4*)(vf + ((size_t)b * N_ + idxs[k]) * C_ + c0), vv);
        const float a = s[k];
#pragma unroll
        for (int c = 0; c < 16; ++c) o[c] += a * vv[c];
    }

    // ---- r = o*inv + Q, block LN ----
    float s1 = 0.f, s2 = 0.f;
#pragma unroll
    for (int c = 0; c < 16; ++c) {
        o[c] = o[c] * inv + qv[c];
        s1 += o[c];
        s2 += o[c] * o[c];
    }
#pragma unroll
    for (int off = 1; off < 16; off <<= 1) {
        s1 += __shfl_xor(s1, off, 64);
        s2 += __shfl_xor(s2, off, 64);
    }
    float mean = s1 * (1.f / C_);
    float var = s2 * (1.f / C_) - mean * mean;
    float rstd = rsqrtf(var + 1e-5f);

    const float a = alpha[row * 3 + iblk];
    const float* gp = lng + iblk * C_ + c0;
    const float* bp = lnb + iblk * C_ + c0;
    float* ap = accum + (size_t)row * C_ + c0;

    // y = a * LN(o); reuse o[] as y storage
#pragma unroll
    for (int j = 0; j < 4; ++j) {
        float4 gg = *(const float4*)(gp + j * 4);
        float4 bb = *(const float4*)(bp + j * 4);
        o[j * 4 + 0] = a * ((o[j * 4 + 0] - mean) * rstd * gg.x + bb.x);
        o[j * 4 + 1] = a * ((o[j * 4 + 1] - mean) * rstd * gg.y + bb.y);
        o[j * 4 + 2] = a * ((o[j * 4 + 2] - mean) * rstd * gg.z + bb.z);
        o[j * 4 + 3] = a * ((o[j * 4 + 3] - mean) * rstd * gg.w + bb.w);
    }

    if (iblk == 0) {
#pragma unroll
        for (int j = 0; j < 4; ++j)
            *(float4*)(ap + j * 4) = make_float4(o[j * 4], o[j * 4 + 1], o[j * 4 + 2], o[j * 4 + 3]);
    } else if (iblk == 1) {
#pragma unroll
        for (int j = 0; j < 4; ++j) {
            float4 p = *(const float4*)(ap + j * 4);
            p.x += o[j * 4 + 0]; p.y += o[j * 4 + 1];
            p.z += o[j * 4 + 2]; p.w += o[j * 4 + 3];
            *(float4*)(ap + j * 4) = p;
        }
    } else {
        // fused final: r = accum + y + x3, LN -> out (in-place on accum)
        const float* xp = x3 + (size_t)row * C_ + c0;
        float r[16];
#pragma unroll
        for (int j = 0; j < 4; ++j) {
            float4 p = *(const float4*)(ap + j * 4);
            float4 xv = *(const float4*)(xp + j * 4);
            r[j * 4 + 0] = p.x + o[j * 4 + 0] + xv.x;
            r[j * 4 + 1] = p.y + o[j * 4 + 1] + xv.y;
            r[j * 4 + 2] = p.z + o[j * 4 + 2] + xv.z;
            r[j * 4 + 3] = p.w + o[j * 4 + 3] + xv.w;
        }
        float t1 = 0.f, t2 = 0.f;
#pragma unroll
        for (int c = 0; c < 16; ++c) {
            t1 += r[c];
            t2 += r[c] * r[c];
        }
#pragma unroll
        for (int off = 1; off < 16; off <<= 1) {
            t1 += __shfl_xor(t1, off, 64);
            t2 += __shfl_xor(t2, off, 64);
        }
        mean = t1 * (1.f / C_);
        var = t2 * (1.f / C_) - mean * mean;
        rstd = rsqrtf(var + 1e-5f);
        const float* fg = fng + c0;
        const float* fb = fnb + c0;
#pragma unroll
        for (int j = 0; j < 4; ++j) {
            float4 gg = *(const float4*)(fg + j * 4);
            float4 bb = *(const float4*)(fb + j * 4);
            float4 y;
            y.x = (r[j * 4 + 0] - mean) * rstd * gg.x + bb.x;
            y.y = (r[j * 4 + 1] - mean) * rstd * gg.y + bb.y;
            y.z = (r[j * 4 + 2] - mean) * rstd * gg.z + bb.z;
            y.w = (r[j * 4 + 3] - mean) * rstd * gg.w + bb.w;
            *(float4*)(ap + j * 4) = y;
        }
    }
}

extern "C" void kernel_launch(void* const* d_in, const int* in_sizes, int n_in,
                              void* d_out, int out_size, void* d_ws, size_t ws_size,
                              hipStream_t stream) {
    const float* x0 = (const float*)d_in[0];
    const float* x1 = (const float*)d_in[1];
    const float* x2 = (const float*)d_in[2];
    const float* x3 = (const float*)d_in[3];
    const int* knn = (const int*)d_in[4];
    const float* Wq = (const float*)d_in[5];
    const float* bq = (const float*)d_in[6];
    const float* Wk = (const float*)d_in[7];
    const float* bk = (const float*)d_in[8];
    const float* Wv = (const float*)d_in[9];
    const float* bv = (const float*)d_in[10];
    const float* ln_g = (const float*)d_in[11];
    const float* ln_b = (const float*)d_in[12];
    const float* Wg1 = (const float*)d_in[13];
    const float* bg1 = (const float*)d_in[14];
    const float* Wg2 = (const float*)d_in[15];
    const float* bg2 = (const float*)d_in[16];
    const float* fn_g = (const float*)d_in[17];
    const float* fn_b = (const float*)d_in[18];
    float* out = (float*)d_out;

    unsigned char* w8 = (unsigned char*)d_ws;
    const size_t XBF = (size_t)MPAD * C_ * 2;   // bf16 M x 256
    const size_t X8 = (size_t)MPAD * C_;        // fp8  M x 256
    const size_t HBF = (size_t)MPAD * H_ * 2;
    const size_t WBLOB = (size_t)3 * C_ * C_ * 2;

    unsigned short* x3bf = (unsigned short*)(w8);
    unsigned short* xqbf = (unsigned short*)(w8 + XBF);       // Q in-place
    unsigned char* kf8 = w8 + 2 * XBF;
    unsigned char* vf8 = w8 + 2 * XBF + X8;
    unsigned short* Hbf = (unsigned short*)(w8 + 2 * XBF + 2 * X8);
    unsigned short* wqbf = (unsigned short*)(w8 + 2 * XBF + 2 * X8 + HBF);
    unsigned short* wkbf = (unsigned short*)(w8 + 2 * XBF + 2 * X8 + HBF + WBLOB);
    unsigned short* wvbf = (unsigned short*)(w8 + 2 * XBF + 2 * X8 + HBF + 2 * WBLOB);
    unsigned short* wg1bf = (unsigned short*)(w8 + 2 * XBF + 2 * X8 + HBF + 3 * WBLOB);
    float* alpha = (float*)(w8 + 2 * XBF + 2 * X8 + HBF + 3 * WBLOB + (size_t)H_ * C_ * 2);
    // total ~74 MB

    const int xn4 = ROWS * C_ / 4;
    const int wn4 = 3 * C_ * C_ / 4;

    cvt_kernel<<<(xn4 + 255) / 256, 256, 0, stream>>>(x3, x3bf, xn4);
    cvtw_kernel<<<dim3((wn4 + 255) / 256, 4), 256, 0, stream>>>(
        Wq, Wk, Wv, Wg1, wqbf, wkbf, wvbf, wg1bf);

    // gate layer 1 + stage 2
    gemm_bf16<<<dim3(MT, 1, 1), 256, 0, stream>>>(x3bf, wg1bf, bg1, Hbf, ROWS, H_);
    gate2_kernel<<<ROWS / 4, 256, 0, stream>>>(Hbf, Wg2, bg2, alpha);

    const float* xq[3] = {x0, x1, x2};
    for (int i = 0; i < 3; ++i) {
        cvt_kernel<<<(xn4 + 255) / 256, 256, 0, stream>>>(xq[i], xqbf, xn4);
        gemm_qkv512<<<dim3(MT, 1, 3), 512, 0, stream>>>(
            xqbf, x3bf, wqbf + (size_t)i * C_ * C_, wkbf + (size_t)i * C_ * C_,
            wvbf + (size_t)i * C_ * C_, bq + i * C_, bk + i * C_, bv + i * C_,
            xqbf, kf8, vf8, ROWS);
        attn_kernel<<<ROWS / 16, 256, 0, stream>>>(xqbf, kf8, vf8, knn, alpha,
                                                   ln_g, ln_b, out, x3, fn_g,
                                                   fn_b, i);
    }
}